// Round 1
// baseline (4912.394 us; speedup 1.0000x reference)
//
#include <hip/hip_runtime.h>
#include <hip/hip_bf16.h>
#include <math.h>

// ---------------------------------------------------------------------------
// KVPLM Star Encoder (BERT-base-like): 12 layers, H=768, NH=12, F=3072,
// B=16, S=512. fp32 weights/activations in global; bf16 MFMA internally.
// Round 0: correctness + m97-structure GEMM + flash MFMA attention.
// ---------------------------------------------------------------------------

#define L_   12
#define H_   768
#define NH_  12
#define DH_  64
#define F_   3072
#define B_   16
#define S_   512
#define NTOK (B_ * S_)   // 8192

typedef __attribute__((ext_vector_type(8))) __bf16 bf16x8;
typedef __attribute__((ext_vector_type(4))) float  f32x4;

static __device__ __forceinline__ f32x4 mfma16(bf16x8 a, bf16x8 b, f32x4 c) {
  return __builtin_amdgcn_mfma_f32_16x16x32_bf16(a, b, c, 0, 0, 0);
}

static __device__ __forceinline__ void load_lds16(const void* g, void* l) {
  __builtin_amdgcn_global_load_lds(
      (const __attribute__((address_space(1))) void*)g,
      (__attribute__((address_space(3))) void*)l, 16, 0, 0);
}

// ---------------------------------------------------------------------------
// Weight transpose+convert: in fp32 [Z][R][C] -> out bf16 [Z][C][R]
// ---------------------------------------------------------------------------
__global__ __launch_bounds__(256) void transpose_k(const float* __restrict__ in,
                                                   __bf16* __restrict__ out,
                                                   int R, int C) {
  __shared__ float t[32][33];
  const int z = blockIdx.z;
  const float* inz = in + (size_t)z * R * C;
  __bf16* outz = out + (size_t)z * R * C;
  const int c0 = blockIdx.x * 32, r0 = blockIdx.y * 32;
  const int tx = threadIdx.x, ty = threadIdx.y;
#pragma unroll
  for (int i = 0; i < 32; i += 8)
    t[ty + i][tx] = inz[(size_t)(r0 + ty + i) * C + c0 + tx];
  __syncthreads();
#pragma unroll
  for (int i = 0; i < 32; i += 8)
    outz[(size_t)(c0 + ty + i) * R + r0 + tx] = (__bf16)t[tx][ty + i];
}

// ---------------------------------------------------------------------------
// GEMM: C[M,N] = A[M,K] (bf16) * Bt[N,K]^T (bf16) + bias. m97 structure:
// 128x128 tile, BK=32, 4 waves (2x2 of 64x64), global_load_lds width 16.
// EPI: 0 = none, 1 = exact GELU.  OUTBF: write bf16 (else fp32).
// All shapes divide evenly (M%128==0, N%128==0, K%32==0).
// ---------------------------------------------------------------------------
template <int EPI, int OUTBF>
__global__ __launch_bounds__(256) void gemm_bt(const __bf16* __restrict__ A,
                                               const __bf16* __restrict__ Bt,
                                               const float* __restrict__ bias,
                                               float* __restrict__ Cf,
                                               __bf16* __restrict__ Cb,
                                               int M, int N, int K) {
  __shared__ __bf16 As[128 * 32];
  __shared__ __bf16 Bs[128 * 32];
  const int tid = threadIdx.x;
  const int wid = tid >> 6, lane = tid & 63;
  const int bm = blockIdx.y << 7, bn = blockIdx.x << 7;
  const int wr = ((wid >> 1) << 6), wc = ((wid & 1) << 6);

  // staging: each wave covers 32 rows of A-tile and 32 rows of Bt-tile
  const int rowS = (wid << 5) + (lane >> 2);
  const int kkS = (lane & 3) << 3;
  const __bf16* ga0 = A + (size_t)(bm + rowS) * K + kkS;
  const __bf16* ga1 = ga0 + (size_t)16 * K;
  const __bf16* gb0 = Bt + (size_t)(bn + rowS) * K + kkS;
  const __bf16* gb1 = gb0 + (size_t)16 * K;
  __bf16* lA0 = &As[wid << 10];
  __bf16* lA1 = lA0 + 512;
  __bf16* lB0 = &Bs[wid << 10];
  __bf16* lB1 = lB0 + 512;

  f32x4 acc[4][4] = {};
  const int frow = lane & 15;          // fragment row/col within 16
  const int fk = (lane >> 4) << 3;     // fragment k-offset (8 contiguous)
  const int nk = K >> 5;

  for (int kt = 0; kt < nk; ++kt) {
    __syncthreads();  // previous compute done before overwriting LDS
    load_lds16(ga0, lA0);
    load_lds16(ga1, lA1);
    load_lds16(gb0, lB0);
    load_lds16(gb1, lB1);
    ga0 += 32; ga1 += 32; gb0 += 32; gb1 += 32;
    __syncthreads();  // vmcnt(0) drained by compiler before barrier

    bf16x8 af[4], bfv[4];
#pragma unroll
    for (int i = 0; i < 4; ++i)
      af[i] = *(const bf16x8*)&As[(wr + (i << 4) + frow) * 32 + fk];
#pragma unroll
    for (int i = 0; i < 4; ++i)
      bfv[i] = *(const bf16x8*)&Bs[(wc + (i << 4) + frow) * 32 + fk];
#pragma unroll
    for (int mi = 0; mi < 4; ++mi)
#pragma unroll
      for (int ni = 0; ni < 4; ++ni)
        acc[mi][ni] = mfma16(af[mi], bfv[ni], acc[mi][ni]);
  }

  // epilogue: C/D layout col=lane&15, row=(lane>>4)*4+r  [m89 verified]
  const int r0 = (lane >> 4) << 2;
  const int c0 = lane & 15;
#pragma unroll
  for (int ni = 0; ni < 4; ++ni) {
    const int col = bn + wc + (ni << 4) + c0;
    const float bv = bias[col];
#pragma unroll
    for (int mi = 0; mi < 4; ++mi) {
      const int row = bm + wr + (mi << 4) + r0;
#pragma unroll
      for (int r = 0; r < 4; ++r) {
        float v = acc[mi][ni][r] + bv;
        if (EPI == 1) v = 0.5f * v * (1.0f + erff(v * 0.70710678118654752f));
        if (OUTBF)
          Cb[(size_t)(row + r) * N + col] = (__bf16)v;
        else
          Cf[(size_t)(row + r) * N + col] = v;
      }
    }
  }
}

// ---------------------------------------------------------------------------
// Flash attention: one block per (h, b). K/V staged fully in LDS (padded),
// 4 waves each own q-tiles of 16 rows; online softmax over key-tiles of 32.
// ---------------------------------------------------------------------------
__global__ __launch_bounds__(256) void attn_kernel(const __bf16* __restrict__ q,
                                                   const __bf16* __restrict__ kg,
                                                   const __bf16* __restrict__ vg,
                                                   const int* __restrict__ amask,
                                                   __bf16* __restrict__ ctx) {
  __shared__ __bf16 Kl[S_][72];        // [key][d]  (pad 64->72)
  __shared__ __bf16 Vt[DH_][S_ + 8];   // [d][key]  (pad 512->520)
  __shared__ float extm[S_];
  __shared__ __bf16 Pl[4][16][56];     // per-wave P tile (pad 32->56)
  const int h = blockIdx.x, b = blockIdx.y;
  const int tid = threadIdx.x, wid = tid >> 6, lane = tid & 63;
  const size_t base = ((size_t)b * S_) * H_ + (size_t)h * DH_;

  for (int c = tid; c < S_ * DH_ / 8; c += 256) {
    const int s = c >> 3, d8 = (c & 7) << 3;
    bf16x8 kv = *(const bf16x8*)(kg + base + (size_t)s * H_ + d8);
    *(bf16x8*)&Kl[s][d8] = kv;
    bf16x8 vv = *(const bf16x8*)(vg + base + (size_t)s * H_ + d8);
#pragma unroll
    for (int j = 0; j < 8; ++j) Vt[d8 + j][s] = vv[j];
  }
  for (int i = tid; i < S_; i += 256)
    extm[i] = (1.0f - (float)amask[b * S_ + i]) * -10000.0f;
  __syncthreads();

  const int c0 = lane & 15, g4 = lane >> 4;
  for (int qt = wid; qt < S_ / 16; qt += 4) {
    const __bf16* qrow = q + base + (size_t)(qt * 16 + c0) * H_ + (g4 << 3);
    const bf16x8 qf0 = *(const bf16x8*)qrow;
    const bf16x8 qf1 = *(const bf16x8*)(qrow + 32);
    f32x4 oacc[4] = {};
    float mrow[4] = {-1e30f, -1e30f, -1e30f, -1e30f};
    float lsum[4] = {0.f, 0.f, 0.f, 0.f};

    for (int kt = 0; kt < 16; ++kt) {
      f32x4 sc[2];
#pragma unroll
      for (int f = 0; f < 2; ++f) {
        const int key = kt * 32 + f * 16 + c0;
        const bf16x8 kf0 = *(const bf16x8*)&Kl[key][g4 << 3];
        const bf16x8 kf1 = *(const bf16x8*)&Kl[key][32 + (g4 << 3)];
        f32x4 z = {};
        z = mfma16(qf0, kf0, z);
        z = mfma16(qf1, kf1, z);
        const float e = extm[key];
#pragma unroll
        for (int r = 0; r < 4; ++r) sc[f][r] = z[r] * 0.125f + e;
      }
      float al[4];
#pragma unroll
      for (int r = 0; r < 4; ++r) {
        float mx = fmaxf(sc[0][r], sc[1][r]);
        mx = fmaxf(mx, __shfl_xor(mx, 1, 64));
        mx = fmaxf(mx, __shfl_xor(mx, 2, 64));
        mx = fmaxf(mx, __shfl_xor(mx, 4, 64));
        mx = fmaxf(mx, __shfl_xor(mx, 8, 64));
        const float mn = fmaxf(mrow[r], mx);
        al[r] = __expf(mrow[r] - mn);
        mrow[r] = mn;
        const float p0 = __expf(sc[0][r] - mn);
        const float p1 = __expf(sc[1][r] - mn);
        sc[0][r] = p0; sc[1][r] = p1;
        float rs = p0 + p1;
        rs += __shfl_xor(rs, 1, 64);
        rs += __shfl_xor(rs, 2, 64);
        rs += __shfl_xor(rs, 4, 64);
        rs += __shfl_xor(rs, 8, 64);
        lsum[r] = lsum[r] * al[r] + rs;
      }
#pragma unroll
      for (int f = 0; f < 2; ++f)
#pragma unroll
        for (int r = 0; r < 4; ++r)
          Pl[wid][g4 * 4 + r][f * 16 + c0] = (__bf16)sc[f][r];
#pragma unroll
      for (int dt = 0; dt < 4; ++dt)
#pragma unroll
        for (int r = 0; r < 4; ++r) oacc[dt][r] *= al[r];
      // P (written above by this wave, in-order DS) -> A-fragment
      const bf16x8 pa = *(const bf16x8*)&Pl[wid][c0][g4 << 3];
#pragma unroll
      for (int dt = 0; dt < 4; ++dt) {
        const bf16x8 vf =
            *(const bf16x8*)&Vt[dt * 16 + c0][kt * 32 + (g4 << 3)];
        oacc[dt] = mfma16(pa, vf, oacc[dt]);
      }
    }
    float inv[4];
#pragma unroll
    for (int r = 0; r < 4; ++r) inv[r] = 1.0f / lsum[r];
#pragma unroll
    for (int dt = 0; dt < 4; ++dt)
#pragma unroll
      for (int r = 0; r < 4; ++r)
        ctx[base + (size_t)(qt * 16 + g4 * 4 + r) * H_ + dt * 16 + c0] =
            (__bf16)(oacc[dt][r] * inv[r]);
  }
}

// ---------------------------------------------------------------------------
// Residual add + LayerNorm: x = LN(x + t) * g + b; also emits bf16 mirror.
// One block (256 thr) per token; each thread owns 3 of 768 elements.
// ---------------------------------------------------------------------------
__global__ __launch_bounds__(256) void addln_kernel(float* __restrict__ x,
                                                    const float* __restrict__ t,
                                                    const float* __restrict__ g,
                                                    const float* __restrict__ bb,
                                                    __bf16* __restrict__ xb) {
  const int tok = blockIdx.x, tid = threadIdx.x;
  float* xr = x + (size_t)tok * H_;
  const float* tr = t + (size_t)tok * H_;
  float v0 = xr[tid] + tr[tid];
  float v1 = xr[tid + 256] + tr[tid + 256];
  float v2 = xr[tid + 512] + tr[tid + 512];
  float s = v0 + v1 + v2;
  float s2 = v0 * v0 + v1 * v1 + v2 * v2;
  __shared__ float red1[4], red2[4];
#pragma unroll
  for (int o = 32; o > 0; o >>= 1) {
    s += __shfl_xor(s, o, 64);
    s2 += __shfl_xor(s2, o, 64);
  }
  if ((tid & 63) == 0) { red1[tid >> 6] = s; red2[tid >> 6] = s2; }
  __syncthreads();
  s = red1[0] + red1[1] + red1[2] + red1[3];
  s2 = red2[0] + red2[1] + red2[2] + red2[3];
  const float mean = s * (1.0f / 768.0f);
  const float var = s2 * (1.0f / 768.0f) - mean * mean;
  const float rstd = rsqrtf(var + 1e-12f);
  const float y0 = (v0 - mean) * rstd * g[tid] + bb[tid];
  const float y1 = (v1 - mean) * rstd * g[tid + 256] + bb[tid + 256];
  const float y2 = (v2 - mean) * rstd * g[tid + 512] + bb[tid + 512];
  xr[tid] = y0; xr[tid + 256] = y1; xr[tid + 512] = y2;
  __bf16* xbr = xb + (size_t)tok * H_;
  xbr[tid] = (__bf16)y0; xbr[tid + 256] = (__bf16)y1; xbr[tid + 512] = (__bf16)y2;
}

// ---------------------------------------------------------------------------
// Embedding (word/star select + pos + type) + LN.
// ---------------------------------------------------------------------------
__global__ __launch_bounds__(256) void embed_kernel(
    const int* __restrict__ ids, const int* __restrict__ tt,
    const float* __restrict__ we, const float* __restrict__ se,
    const float* __restrict__ pe, const float* __restrict__ te,
    const float* __restrict__ g, const float* __restrict__ bb,
    float* __restrict__ x, __bf16* __restrict__ xb) {
  const int tok = blockIdx.x, tid = threadIdx.x;
  const int sp = tok & (S_ - 1);
  const int id = ids[tok];
  const float* e = (id >= 30700) ? se + (size_t)(id - 30700) * H_
                                 : we + (size_t)id * H_;
  const float* pr = pe + (size_t)sp * H_;
  const float* ty = te + (size_t)tt[tok] * H_;
  float v0 = e[tid] + pr[tid] + ty[tid];
  float v1 = e[tid + 256] + pr[tid + 256] + ty[tid + 256];
  float v2 = e[tid + 512] + pr[tid + 512] + ty[tid + 512];
  float s = v0 + v1 + v2;
  float s2 = v0 * v0 + v1 * v1 + v2 * v2;
  __shared__ float red1[4], red2[4];
#pragma unroll
  for (int o = 32; o > 0; o >>= 1) {
    s += __shfl_xor(s, o, 64);
    s2 += __shfl_xor(s2, o, 64);
  }
  if ((tid & 63) == 0) { red1[tid >> 6] = s; red2[tid >> 6] = s2; }
  __syncthreads();
  s = red1[0] + red1[1] + red1[2] + red1[3];
  s2 = red2[0] + red2[1] + red2[2] + red2[3];
  const float mean = s * (1.0f / 768.0f);
  const float var = s2 * (1.0f / 768.0f) - mean * mean;
  const float rstd = rsqrtf(var + 1e-12f);
  float* xr = x + (size_t)tok * H_;
  __bf16* xbr = xb + (size_t)tok * H_;
  const float y0 = (v0 - mean) * rstd * g[tid] + bb[tid];
  const float y1 = (v1 - mean) * rstd * g[tid + 256] + bb[tid + 256];
  const float y2 = (v2 - mean) * rstd * g[tid + 512] + bb[tid + 512];
  xr[tid] = y0; xr[tid + 256] = y1; xr[tid + 512] = y2;
  xbr[tid] = (__bf16)y0; xbr[tid + 256] = (__bf16)y1; xbr[tid + 512] = (__bf16)y2;
}

// ---------------------------------------------------------------------------
// Pooler: pooled[b] = tanh(x[b,0,:] @ poolW + pool_b). 16 blocks.
// ---------------------------------------------------------------------------
__global__ __launch_bounds__(256) void pool_kernel(const float* __restrict__ x,
                                                   const __bf16* __restrict__ wT,
                                                   const float* __restrict__ pb,
                                                   float* __restrict__ out) {
  const int b = blockIdx.x, tid = threadIdx.x;
  __shared__ float xr[H_];
  for (int i = tid; i < H_; i += 256) xr[i] = x[(size_t)b * S_ * H_ + i];
  __syncthreads();
  for (int n = tid; n < H_; n += 256) {
    const __bf16* w = wT + (size_t)n * H_;
    float acc = 0.f;
    for (int k = 0; k < H_; ++k) acc += xr[k] * (float)w[k];
    out[(size_t)b * H_ + n] = tanhf(acc + pb[n]);
  }
}

// ---------------------------------------------------------------------------
extern "C" void kernel_launch(void* const* d_in, const int* in_sizes, int n_in,
                              void* d_out, int out_size, void* d_ws,
                              size_t ws_size, hipStream_t stream) {
  (void)in_sizes; (void)n_in; (void)out_size;
  const int* ids = (const int*)d_in[0];
  const int* am = (const int*)d_in[1];
  const int* tt = (const int*)d_in[2];
  const float* we = (const float*)d_in[3];
  const float* se = (const float*)d_in[4];
  const float* pe = (const float*)d_in[5];
  const float* te = (const float*)d_in[6];
  const float* eg = (const float*)d_in[7];
  const float* ebb = (const float*)d_in[8];
  const float* Wq = (const float*)d_in[9];
  const float* bq = (const float*)d_in[10];
  const float* Wk = (const float*)d_in[11];
  const float* bk = (const float*)d_in[12];
  const float* Wv = (const float*)d_in[13];
  const float* bv = (const float*)d_in[14];
  const float* Wo = (const float*)d_in[15];
  const float* bo = (const float*)d_in[16];
  const float* g1 = (const float*)d_in[17];
  const float* b1 = (const float*)d_in[18];
  const float* Wi = (const float*)d_in[19];
  const float* bi = (const float*)d_in[20];
  const float* Wf = (const float*)d_in[21];
  const float* bf_ = (const float*)d_in[22];
  const float* g2 = (const float*)d_in[23];
  const float* b2 = (const float*)d_in[24];
  const float* pw = (const float*)d_in[25];
  const float* pb = (const float*)d_in[26];

  // ---- workspace layout (bf16 elements unless noted) ----
  const size_t WSQ = (size_t)L_ * H_ * H_;   // 7,077,888
  const size_t WSF = (size_t)L_ * H_ * F_;   // 28,311,552
  __bf16* wTq_ = (__bf16*)d_ws;
  __bf16* wTk_ = wTq_ + WSQ;
  __bf16* wTv_ = wTk_ + WSQ;
  __bf16* wTo_ = wTv_ + WSQ;
  __bf16* wTi_ = wTo_ + WSQ;
  __bf16* wTf_ = wTi_ + WSF;
  __bf16* wTp_ = wTf_ + WSF;
  __bf16* xb = wTp_ + (size_t)H_ * H_;
  __bf16* qb = xb + (size_t)NTOK * H_;
  __bf16* kb = qb + (size_t)NTOK * H_;
  __bf16* vb = kb + (size_t)NTOK * H_;
  __bf16* cb = vb + (size_t)NTOK * H_;
  __bf16* mid = cb + (size_t)NTOK * H_;
  float* t0 = (float*)(mid + (size_t)NTOK * F_);
  const size_t needed = (size_t)((char*)(t0 + (size_t)NTOK * H_) - (char*)d_ws);
  if (ws_size < needed) return;  // insufficient scratch: leave poison (visible failure)

  float* x = (float*)d_out;
  float* pooled = x + (size_t)NTOK * H_;

  const dim3 tb(32, 8);
  transpose_k<<<dim3(24, 24, 12), tb, 0, stream>>>(Wq, wTq_, H_, H_);
  transpose_k<<<dim3(24, 24, 12), tb, 0, stream>>>(Wk, wTk_, H_, H_);
  transpose_k<<<dim3(24, 24, 12), tb, 0, stream>>>(Wv, wTv_, H_, H_);
  transpose_k<<<dim3(24, 24, 12), tb, 0, stream>>>(Wo, wTo_, H_, H_);
  transpose_k<<<dim3(96, 24, 12), tb, 0, stream>>>(Wi, wTi_, H_, F_);
  transpose_k<<<dim3(24, 96, 12), tb, 0, stream>>>(Wf, wTf_, F_, H_);
  transpose_k<<<dim3(24, 24, 1), tb, 0, stream>>>(pw, wTp_, H_, H_);

  embed_kernel<<<NTOK, 256, 0, stream>>>(ids, tt, we, se, pe, te, eg, ebb, x, xb);

  for (int l = 0; l < L_; ++l) {
    const __bf16* wq = wTq_ + (size_t)l * H_ * H_;
    const __bf16* wk = wTk_ + (size_t)l * H_ * H_;
    const __bf16* wv = wTv_ + (size_t)l * H_ * H_;
    const __bf16* wo = wTo_ + (size_t)l * H_ * H_;
    const __bf16* wi = wTi_ + (size_t)l * H_ * F_;
    const __bf16* wf = wTf_ + (size_t)l * H_ * F_;

    gemm_bt<0, 1><<<dim3(H_ / 128, NTOK / 128), 256, 0, stream>>>(
        xb, wq, bq + l * H_, nullptr, qb, NTOK, H_, H_);
    gemm_bt<0, 1><<<dim3(H_ / 128, NTOK / 128), 256, 0, stream>>>(
        xb, wk, bk + l * H_, nullptr, kb, NTOK, H_, H_);
    gemm_bt<0, 1><<<dim3(H_ / 128, NTOK / 128), 256, 0, stream>>>(
        xb, wv, bv + l * H_, nullptr, vb, NTOK, H_, H_);

    attn_kernel<<<dim3(NH_, B_), 256, 0, stream>>>(qb, kb, vb, am, cb);

    gemm_bt<0, 0><<<dim3(H_ / 128, NTOK / 128), 256, 0, stream>>>(
        cb, wo, bo + l * H_, t0, nullptr, NTOK, H_, H_);
    addln_kernel<<<NTOK, 256, 0, stream>>>(x, t0, g1 + l * H_, b1 + l * H_, xb);

    gemm_bt<1, 1><<<dim3(F_ / 128, NTOK / 128), 256, 0, stream>>>(
        xb, wi, bi + l * F_, nullptr, mid, NTOK, F_, H_);
    gemm_bt<0, 0><<<dim3(H_ / 128, NTOK / 128), 256, 0, stream>>>(
        mid, wf, bf_ + l * H_, t0, nullptr, NTOK, H_, F_);
    addln_kernel<<<NTOK, 256, 0, stream>>>(x, t0, g2 + l * H_, b2 + l * H_, xb);
  }

  pool_kernel<<<B_, 256, 0, stream>>>(x, wTp_, pb, pooled);
}